// Round 5
// baseline (1164.178 us; speedup 1.0000x reference)
//
#include <hip/hip_runtime.h>

typedef __bf16 bf16x8 __attribute__((ext_vector_type(8)));
typedef __bf16 bf16x4 __attribute__((ext_vector_type(4)));
typedef float  f32x4  __attribute__((ext_vector_type(4)));
typedef unsigned short u16;
typedef unsigned short us4 __attribute__((ext_vector_type(4)));

__device__ __forceinline__ u16 f2bf(float f) {
  __bf16 h = (__bf16)f;
  return __builtin_bit_cast(u16, h);
}

__device__ __forceinline__ void gload16(const void* g, void* l) {
  __builtin_amdgcn_global_load_lds(
      (const __attribute__((address_space(1))) unsigned int*)(g),
      (__attribute__((address_space(3))) unsigned int*)(l), 16, 0, 0);
}

__device__ __forceinline__ void barrier_lgkm() {
  asm volatile("s_waitcnt lgkmcnt(0)" ::: "memory");
  __builtin_amdgcn_s_barrier();
  asm volatile("" ::: "memory");
}
template <int N> __device__ __forceinline__ void vmwait() {
  asm volatile("s_waitcnt vmcnt(%0)" :: "n"(N) : "memory");
}

// K=16 bf16 MFMA (instruction exists on gfx950; no stable builtin name -> asm)
__device__ __forceinline__ f32x4 mfma16(bf16x4 a, bf16x4 b, f32x4 c) {
  asm("v_mfma_f32_16x16x16_bf16 %0, %1, %2, %0" : "+v"(c) : "v"(a), "v"(b));
  return c;
}

// ---------------- GroupNorm: pass 1 (partial sums) ----------------
__global__ void gn_partial(const float* __restrict__ x, float* __restrict__ part) {
  const int chunk = blockIdx.x, g = blockIdx.y, b = blockIdx.z;
  const int tid = threadIdx.x;
  float s = 0.f, ss = 0.f;
  const float* xb = x + ((size_t)(b * 4096 + chunk * 512)) * 512 + g * 16;
  for (int i = tid; i < 2048; i += 256) {
    const int sp = i >> 2, c4 = (i & 3) << 2;
    const float4 v = *(const float4*)(xb + (size_t)sp * 512 + c4);
    s  += v.x + v.y + v.z + v.w;
    ss += v.x * v.x + v.y * v.y + v.z * v.z + v.w * v.w;
  }
  for (int m = 32; m; m >>= 1) { s += __shfl_xor(s, m); ss += __shfl_xor(ss, m); }
  __shared__ float red[8];
  const int w = tid >> 6;
  if ((tid & 63) == 0) { red[w * 2] = s; red[w * 2 + 1] = ss; }
  __syncthreads();
  if (tid == 0) {
    float S = 0.f, SS = 0.f;
    for (int i = 0; i < 4; ++i) { S += red[2 * i]; SS += red[2 * i + 1]; }
    const int idx = ((b * 32 + g) * 8 + chunk) * 2;
    part[idx] = S; part[idx + 1] = SS;
  }
}

// ---------------- GroupNorm: pass 2 (finalize) ----------------
__global__ void gn_finalize(const float* __restrict__ part, float* __restrict__ stats) {
  const int t = threadIdx.x;  // 128 = 4*32
  if (t < 128) {
    float S = 0.f, SS = 0.f;
    for (int i = 0; i < 8; ++i) { S += part[(t * 8 + i) * 2]; SS += part[(t * 8 + i) * 2 + 1]; }
    const float mean = S * (1.0f / 65536.0f);
    const float var  = SS * (1.0f / 65536.0f) - mean * mean;
    stats[t * 2] = mean;
    stats[t * 2 + 1] = rsqrtf(var + 1e-6f);
  }
}

// ---------------- GroupNorm: pass 3 (normalize + cast bf16) ----------------
__global__ void gn_apply(const float* __restrict__ x, const float* __restrict__ gamma,
                         const float* __restrict__ beta, const float* __restrict__ stats,
                         u16* __restrict__ h) {
  const size_t i = (size_t)blockIdx.x * 256 + threadIdx.x;
  const size_t e = i * 4;
  const int c = (int)(e & 511);
  const int b = (int)(e >> 21);
  const int g = c >> 4;
  const float mean = stats[(b * 32 + g) * 2];
  const float rstd = stats[(b * 32 + g) * 2 + 1];
  const float4 xv = *(const float4*)(x + e);
  const float4 gv = *(const float4*)(gamma + c);
  const float4 bv = *(const float4*)(beta + c);
  us4 hv;
  hv.x = f2bf((xv.x - mean) * rstd * gv.x + bv.x);
  hv.y = f2bf((xv.y - mean) * rstd * gv.y + bv.y);
  hv.z = f2bf((xv.z - mean) * rstd * gv.z + bv.z);
  hv.w = f2bf((xv.w - mean) * rstd * gv.w + bv.w);
  *(us4*)(h + e) = hv;
}

// ---------------- fused weight transpose + cast (all 4 weights) ----------------
__global__ void wcast_t4(const float* __restrict__ wq, const float* __restrict__ wk,
                         const float* __restrict__ wv, const float* __restrict__ wo,
                         u16* __restrict__ wT) {
  const int idx = blockIdx.x * 256 + threadIdx.x;  // 0..1048575
  const int which = idx >> 18;
  const int rr = idx & 262143;
  const float* w = (which == 0) ? wq : (which == 1) ? wk : (which == 2) ? wv : wo;
  const int n = rr >> 9, k = rr & 511;
  wT[idx] = f2bf(w[k * 512 + n]);
}

#define GEMM_STAGE(buf, t)                                                       \
  {                                                                              \
    const int k0 = (t) * 32;                                                     \
    _Pragma("unroll")                                                            \
    for (int i = 0; i < 2; ++i) {                                                \
      const int cid = tid + i * 256;                                             \
      const int row = cid >> 2, cb = cid & 3;                                    \
      const int sc = (cb ^ (row & 3)) << 3;                                      \
      gload16(A + (size_t)(brow + row) * 512 + k0 + sc, &lA[buf][cid << 3]);     \
      gload16(Bt + (size_t)(bcol0 + row) * 512 + k0 + sc, &lB[buf][cid << 3]);   \
    }                                                                            \
  }

#define GEMM_MAIN                                                                \
  const f32x4 zero4 = {0.f, 0.f, 0.f, 0.f};                                      \
  f32x4 acc[4][4];                                                               \
  _Pragma("unroll") for (int a_ = 0; a_ < 4; ++a_)                               \
  _Pragma("unroll") for (int b_ = 0; b_ < 4; ++b_) acc[a_][b_] = zero4;          \
  GEMM_STAGE(0, 0);                                                              \
  asm volatile("s_waitcnt vmcnt(0)" ::: "memory");                               \
  __syncthreads();                                                               \
  int buf = 0;                                                                   \
  for (int t = 0; t < 16; ++t) {                                                 \
    if (t < 15) GEMM_STAGE(buf ^ 1, t + 1);                                      \
    bf16x8 af[4], bfv[4];                                                        \
    _Pragma("unroll") for (int f = 0; f < 4; ++f) {                              \
      const int ra = wr * 64 + f * 16 + l15;                                     \
      af[f] = *(const bf16x8*)(&lA[buf][(ra << 5) + ((lq ^ (ra & 3)) << 3)]);    \
      const int rb = wc * 64 + f * 16 + l15;                                     \
      bfv[f] = *(const bf16x8*)(&lB[buf][(rb << 5) + ((lq ^ (rb & 3)) << 3)]);   \
    }                                                                            \
    _Pragma("unroll") for (int fa = 0; fa < 4; ++fa)                             \
    _Pragma("unroll") for (int fb = 0; fb < 4; ++fb)                             \
      acc[fa][fb] = __builtin_amdgcn_mfma_f32_16x16x32_bf16(af[fa], bfv[fb],     \
                                                            acc[fa][fb], 0, 0, 0);\
    asm volatile("s_waitcnt vmcnt(0)" ::: "memory");                             \
    __syncthreads();                                                             \
    buf ^= 1;                                                                    \
  }

// ---------------- o-projection GEMM: f32 out, +bias +residual ----------------
__global__ __launch_bounds__(256)
void gemm_oproj(const u16* __restrict__ A, const u16* __restrict__ Bt,
                const float* __restrict__ bias, const float* __restrict__ resid,
                float* __restrict__ Cout) {
  const int tid = threadIdx.x;
  const int wid = tid >> 6, l = tid & 63;
  const int wr = wid >> 1, wc = wid & 1;
  const int l15 = l & 15, lq = l >> 4;
  const int brow = blockIdx.x * 128, bcol0 = blockIdx.y * 128;
  __shared__ u16 lA[2][4096];
  __shared__ u16 lB[2][4096];
  GEMM_MAIN
#pragma unroll
  for (int fa = 0; fa < 4; ++fa)
#pragma unroll
    for (int fb = 0; fb < 4; ++fb) {
      const int col = bcol0 + wc * 64 + fb * 16 + l15;
      const float bv = bias[col];
#pragma unroll
      for (int i = 0; i < 4; ++i) {
        const int row = brow + wr * 64 + fa * 16 + lq * 4 + i;
        const size_t idx = (size_t)row * 512 + col;
        Cout[idx] = acc[fa][fb][i] + bv + resid[idx];
      }
    }
}

// ---------------- fused QKV GEMM: grid (128, 12) ----------------
__global__ __launch_bounds__(256)
void gemm_qkv(const u16* __restrict__ A, const u16* __restrict__ wT,
              const float* __restrict__ bq, const float* __restrict__ bk,
              const float* __restrict__ bv_, u16* __restrict__ q,
              u16* __restrict__ k, u16* __restrict__ v8, float qs) {
  const int tid = threadIdx.x;
  const int wid = tid >> 6, l = tid & 63;
  const int wr = wid >> 1, wc = wid & 1;
  const int l15 = l & 15, lq = l >> 4;
  const int which = blockIdx.y >> 2;
  const int brow = blockIdx.x * 128, bcol0 = (blockIdx.y & 3) * 128;
  const u16* Bt = wT + which * 262144;
  const float* bias = (which == 0) ? bq : ((which == 1) ? bk : bv_);
  __shared__ u16 lA[2][4096];
  __shared__ u16 lB[2][4096];
  GEMM_MAIN
#pragma unroll
  for (int fa = 0; fa < 4; ++fa)
#pragma unroll
    for (int fb = 0; fb < 4; ++fb) {
      const int col = bcol0 + wc * 64 + fb * 16 + l15;
      const float bb_ = bias[col];
#pragma unroll
      for (int i = 0; i < 4; ++i) {
        const int row = brow + wr * 64 + fa * 16 + lq * 4 + i;
        const float v = acc[fa][fb][i] + bb_;
        if (which == 0) {
          q[(size_t)row * 512 + col] = f2bf(v * qs);
        } else if (which == 1) {
          k[(size_t)row * 512 + col] = f2bf(v);
        } else {
          const int bb = row >> 12, n = row & 4095;
          // V8 layout with nb-XOR bank swizzle baked in (chunk index ^= block&3)
          v8[((size_t)(bb * 512 + (n >> 3))) * 4096 +
             (size_t)((col ^ ((n >> 3) & 3)) << 3) + (n & 7)] = f2bf(v);
        }
      }
    }
}

// ---------------- flash attention v5: swapped QK^T, in-register softmax ------
// grid (64 qblocks, 4 batches), block 512 = 8 waves = 4 q-groups x 2 kv-streams.
// Per step: 32 kv staged (16 per stream); ONE barrier per step; no S/P in LDS.
__global__ __launch_bounds__(512, 2)
void attn_kernel(const u16* __restrict__ Q, const u16* __restrict__ K,
                 const u16* __restrict__ V8, u16* __restrict__ Oo) {
  const int b = blockIdx.y, qb = blockIdx.x;
  const int tid = threadIdx.x;
  const int wid = tid >> 6, l = tid & 63;
  const int r = wid & 3;     // q-group (16 rows)
  const int s = wid >> 2;    // kv-stream (owns 16 of each step's 32 kv rows)
  const int l15 = l & 15, lq = l >> 4;

  // [2 bufs][K 32KB | V 32KB] = 128KB; +512B for m/l exchange
  __shared__ __align__(1024) char lds[131072 + 512];

  const u16* Kb = K + (size_t)b * 2097152;
  const u16* Vb = V8 + (size_t)b * 2097152;

#define STAGEK(tt)                                                     \
  {                                                                    \
    const u16* ks = Kb + (size_t)((tt) & 127) * 16384;                 \
    char* kd = lds + (((tt) & 1) << 16);                               \
    _Pragma("unroll") for (int i = 0; i < 4; ++i) {                    \
      const int cid = tid + i * 512;                                   \
      const int ob = cid << 4;                                         \
      const int n_ = ob >> 10;                                         \
      const int cb = (ob & 1023) ^ ((n_ & 7) << 4);                    \
      gload16(ks + (size_t)n_ * 512 + (cb >> 1), kd + ob);             \
    }                                                                  \
  }
#define STAGEV(tt)                                                     \
  {                                                                    \
    const u16* vs = Vb + (size_t)((tt) & 127) * 16384;                 \
    char* vd = lds + (((tt) & 1) << 16) + 32768;                       \
    _Pragma("unroll") for (int i = 0; i < 4; ++i) {                    \
      const int cid = tid + i * 512;                                   \
      gload16(vs + (cid << 3), vd + (cid << 4));                       \
    }                                                                  \
  }

  STAGEK(0); STAGEV(0);

  // Q fragments (B-operand layout == row-major load): rows r*16..+16, D=512
  bf16x8 qf[16];
  {
    const u16* qp = Q + ((size_t)(b * 4096 + qb * 64 + r * 16 + l15)) * 512 + lq * 8;
#pragma unroll
    for (int kk = 0; kk < 16; ++kk) qf[kk] = *(const bf16x8*)(qp + kk * 32);
  }
  const f32x4 zero4 = {0.f, 0.f, 0.f, 0.f};
  f32x4 o[32];  // O[16q][512d] per wave: tile f -> cols f*16..+16, rows lq*4+i
#pragma unroll
  for (int f = 0; f < 32; ++f) o[f] = zero4;
  float m_ = -1e30f, l_ = 0.f;

  const int krow = s * 16 + l15;          // K A-frag row within staged tile
  const int kswz = (krow & 7) << 4;
  const int nb3 = s * 2 + (lq >> 1);      // V8 sub-block for this lane's kv

#pragma unroll 2
  for (int t = 0; t < 128; ++t) {
    vmwait<0>();
    barrier_lgkm();                  // staged K/V(t) visible to all waves
    STAGEK(t + 1);                   // into buf (t+1)&1, freed by compute(t-1)
    STAGEV(t + 1);

    // ---- S^T = K Q^T : lane holds S^T[kv=lq*4+i][q=l15] ----
    const char* kb = lds + ((t & 1) << 16) + krow * 1024;
    f32x4 se = zero4, so2 = zero4;
    __builtin_amdgcn_s_setprio(1);
#pragma unroll
    for (int kk = 0; kk < 16; kk += 2) {
      const bf16x8 k0 = *(const bf16x8*)(kb + ((kk * 64 + (lq << 4)) ^ kswz));
      se = __builtin_amdgcn_mfma_f32_16x16x32_bf16(k0, qf[kk], se, 0, 0, 0);
      const bf16x8 k1 = *(const bf16x8*)(kb + (((kk + 1) * 64 + (lq << 4)) ^ kswz));
      so2 = __builtin_amdgcn_mfma_f32_16x16x32_bf16(k1, qf[kk + 1], so2, 0, 0, 0);
    }
    __builtin_amdgcn_s_setprio(0);
    const f32x4 sacc = se + so2;

    // ---- in-register online softmax (defer-max THR=8) ----
    float tmax = fmaxf(fmaxf(sacc[0], sacc[1]), fmaxf(sacc[2], sacc[3]));
    tmax = fmaxf(tmax, __shfl_xor(tmax, 16));
    tmax = fmaxf(tmax, __shfl_xor(tmax, 32));
    const bool need = tmax > m_ + 8.0f;
    const float mn = need ? tmax : m_;
    const float al = need ? __expf(m_ - mn) : 1.0f;
    const float p0 = __expf(sacc[0] - mn), p1 = __expf(sacc[1] - mn);
    const float p2 = __expf(sacc[2] - mn), p3 = __expf(sacc[3] - mn);
    float ps = (p0 + p1) + (p2 + p3);
    ps += __shfl_xor(ps, 16);
    ps += __shfl_xor(ps, 32);
    l_ = l_ * al + ps;
    m_ = mn;
    bf16x4 pa;
    pa[0] = (__bf16)p0; pa[1] = (__bf16)p1; pa[2] = (__bf16)p2; pa[3] = (__bf16)p3;

    // ---- rescale O (rare; factors fetched by lane shuffle) ----
    if (__any(need)) {
      float aq[4];
#pragma unroll
      for (int i = 0; i < 4; ++i) aq[i] = __shfl(al, lq * 4 + i);
#pragma unroll
      for (int f = 0; f < 32; ++f) {
        o[f][0] *= aq[0]; o[f][1] *= aq[1]; o[f][2] *= aq[2]; o[f][3] *= aq[3];
      }
    }

    // ---- O += P V : P already in A-frag layout; K=16 MFMA ----
    const char* vbl = lds + ((t & 1) << 16) + 32768 + (nb3 << 13) + ((lq & 1) << 3);
    __builtin_amdgcn_s_setprio(1);
#pragma unroll
    for (int f = 0; f < 32; ++f) {
      const int c = f * 16 + l15;
      const bf16x4 vf = *(const bf16x4*)(vbl + ((c ^ nb3) << 4));
      o[f] = mfma16(pa, vf, o[f]);
    }
    __builtin_amdgcn_s_setprio(0);
  }
#undef STAGEK
#undef STAGEV

  // ---- epilogue: merge the two kv-streams via LDS, store bf16 ----
  vmwait<0>();     // drain stray wrap-around prefetch before LDS reuse
  barrier_lgkm();
  float* mX = (float*)(lds + 131072);  // [4r][16q]
  float* lX = mX + 64;
  float* xo = (float*)(lds + (size_t)r * 32768);
  if (s == 1) {
#pragma unroll
    for (int f = 0; f < 32; ++f)
#pragma unroll
      for (int i = 0; i < 4; ++i)
        xo[(lq * 4 + i) * 512 + f * 16 + l15] = o[f][i];
    if (lq == 0) { mX[r * 16 + l15] = m_; lX[r * 16 + l15] = l_; }
  }
  barrier_lgkm();
  if (s == 0) {
    float w0[4], w1[4], dn[4];
#pragma unroll
    for (int i = 0; i < 4; ++i) {
      const int qi = lq * 4 + i;
      const float m1 = mX[r * 16 + qi], l1 = lX[r * 16 + qi];
      const float m0 = __shfl(m_, qi),  l0 = __shfl(l_, qi);
      const float M = fmaxf(m0, m1);
      w0[i] = __expf(m0 - M);
      w1[i] = __expf(m1 - M);
      dn[i] = 1.0f / (w0[i] * l0 + w1[i] * l1);
    }
    u16* ob = Oo + ((size_t)(b * 4096 + qb * 64 + r * 16)) * 512;
#pragma unroll
    for (int f = 0; f < 32; ++f)
#pragma unroll
      for (int i = 0; i < 4; ++i) {
        const float v1 = xo[(lq * 4 + i) * 512 + f * 16 + l15];
        ob[(size_t)(lq * 4 + i) * 512 + f * 16 + l15] =
            f2bf((w0[i] * o[f][i] + w1[i] * v1) * dn[i]);
      }
  }
}

extern "C" void kernel_launch(void* const* d_in, const int* in_sizes, int n_in,
                              void* d_out, int out_size, void* d_ws, size_t ws_size,
                              hipStream_t stream) {
  const float* x     = (const float*)d_in[0];
  const float* gamma = (const float*)d_in[1];
  const float* beta  = (const float*)d_in[2];
  const float* wq    = (const float*)d_in[3];
  const float* bq    = (const float*)d_in[4];
  const float* wk    = (const float*)d_in[5];
  const float* bk    = (const float*)d_in[6];
  const float* wv    = (const float*)d_in[7];
  const float* bv    = (const float*)d_in[8];
  const float* wo    = (const float*)d_in[9];
  const float* bo    = (const float*)d_in[10];
  float* out = (float*)d_out;

  char* ws = (char*)d_ws;
  const size_t SZ = (size_t)16384 * 512;
  u16* h    = (u16*)(ws);                 // 16 MB
  u16* q    = (u16*)(ws + SZ * 2);        // 16 MB (pre-scaled by C^-0.5)
  u16* k    = (u16*)(ws + SZ * 4);        // 16 MB
  u16* v8   = (u16*)(ws + SZ * 6);        // 16 MB, [B][N/8][C^(blk&3)][8]
  u16* aout = (u16*)(ws + SZ * 8);        // 16 MB
  u16* wT   = (u16*)(ws + SZ * 10);       // 4 x 512KB
  float* part  = (float*)(ws + SZ * 10 + 4 * 262144 * 2);
  float* stats = part + 2048;

  gn_partial<<<dim3(8, 32, 4), 256, 0, stream>>>(x, part);
  gn_finalize<<<1, 128, 0, stream>>>(part, stats);
  gn_apply<<<8192, 256, 0, stream>>>(x, gamma, beta, stats, h);

  wcast_t4<<<4096, 256, 0, stream>>>(wq, wk, wv, wo, wT);

  const float qs = 0.044194173824159216f;  // 512^-0.5
  gemm_qkv<<<dim3(128, 12), 256, 0, stream>>>(h, wT, bq, bk, bv, q, k, v8, qs);

  attn_kernel<<<dim3(64, 4), 512, 0, stream>>>(q, k, v8, aout);

  gemm_oproj<<<dim3(128, 4), 256, 0, stream>>>(aout, wT + 3 * 262144, bo, x, out);
}

// Round 6
// 394.393 us; speedup vs baseline: 2.9518x; 2.9518x over previous
//
#include <hip/hip_runtime.h>

typedef __bf16 bf16x8 __attribute__((ext_vector_type(8)));
typedef float  f32x4  __attribute__((ext_vector_type(4)));
typedef int    i32x4  __attribute__((ext_vector_type(4)));
typedef unsigned short u16;
typedef unsigned short us4 __attribute__((ext_vector_type(4)));

__device__ __forceinline__ u16 f2bf(float f) {
  __bf16 h = (__bf16)f;
  return __builtin_bit_cast(u16, h);
}

__device__ __forceinline__ void gload16(const void* g, void* l) {
  __builtin_amdgcn_global_load_lds(
      (const __attribute__((address_space(1))) unsigned int*)(g),
      (__attribute__((address_space(3))) unsigned int*)(l), 16, 0, 0);
}

__device__ __forceinline__ void barrier_lgkm() {
  asm volatile("s_waitcnt lgkmcnt(0)" ::: "memory");
  __builtin_amdgcn_s_barrier();
  asm volatile("" ::: "memory");
}
template <int N> __device__ __forceinline__ void vmwait() {
  asm volatile("s_waitcnt vmcnt(%0)" :: "n"(N) : "memory");
}

// ---------------- GroupNorm: pass 1 (partial sums) ----------------
__global__ void gn_partial(const float* __restrict__ x, float* __restrict__ part) {
  const int chunk = blockIdx.x, g = blockIdx.y, b = blockIdx.z;
  const int tid = threadIdx.x;
  float s = 0.f, ss = 0.f;
  const float* xb = x + ((size_t)(b * 4096 + chunk * 512)) * 512 + g * 16;
  for (int i = tid; i < 2048; i += 256) {
    const int sp = i >> 2, c4 = (i & 3) << 2;
    const float4 v = *(const float4*)(xb + (size_t)sp * 512 + c4);
    s  += v.x + v.y + v.z + v.w;
    ss += v.x * v.x + v.y * v.y + v.z * v.z + v.w * v.w;
  }
  for (int m = 32; m; m >>= 1) { s += __shfl_xor(s, m); ss += __shfl_xor(ss, m); }
  __shared__ float red[8];
  const int w = tid >> 6;
  if ((tid & 63) == 0) { red[w * 2] = s; red[w * 2 + 1] = ss; }
  __syncthreads();
  if (tid == 0) {
    float S = 0.f, SS = 0.f;
    for (int i = 0; i < 4; ++i) { S += red[2 * i]; SS += red[2 * i + 1]; }
    const int idx = ((b * 32 + g) * 8 + chunk) * 2;
    part[idx] = S; part[idx + 1] = SS;
  }
}

// ---------------- GroupNorm: pass 2 (finalize) ----------------
__global__ void gn_finalize(const float* __restrict__ part, float* __restrict__ stats) {
  const int t = threadIdx.x;  // 128 = 4*32
  if (t < 128) {
    float S = 0.f, SS = 0.f;
    for (int i = 0; i < 8; ++i) { S += part[(t * 8 + i) * 2]; SS += part[(t * 8 + i) * 2 + 1]; }
    const float mean = S * (1.0f / 65536.0f);
    const float var  = SS * (1.0f / 65536.0f) - mean * mean;
    stats[t * 2] = mean;
    stats[t * 2 + 1] = rsqrtf(var + 1e-6f);
  }
}

// ---------------- GroupNorm: pass 3 (normalize + cast bf16) ----------------
__global__ void gn_apply(const float* __restrict__ x, const float* __restrict__ gamma,
                         const float* __restrict__ beta, const float* __restrict__ stats,
                         u16* __restrict__ h) {
  const size_t i = (size_t)blockIdx.x * 256 + threadIdx.x;
  const size_t e = i * 4;
  const int c = (int)(e & 511);
  const int b = (int)(e >> 21);
  const int g = c >> 4;
  const float mean = stats[(b * 32 + g) * 2];
  const float rstd = stats[(b * 32 + g) * 2 + 1];
  const float4 xv = *(const float4*)(x + e);
  const float4 gv = *(const float4*)(gamma + c);
  const float4 bv = *(const float4*)(beta + c);
  us4 hv;
  hv.x = f2bf((xv.x - mean) * rstd * gv.x + bv.x);
  hv.y = f2bf((xv.y - mean) * rstd * gv.y + bv.y);
  hv.z = f2bf((xv.z - mean) * rstd * gv.z + bv.z);
  hv.w = f2bf((xv.w - mean) * rstd * gv.w + bv.w);
  *(us4*)(h + e) = hv;
}

// ---------------- fused weight transpose + cast (all 4 weights) ----------------
__global__ void wcast_t4(const float* __restrict__ wq, const float* __restrict__ wk,
                         const float* __restrict__ wv, const float* __restrict__ wo,
                         u16* __restrict__ wT) {
  const int idx = blockIdx.x * 256 + threadIdx.x;  // 0..1048575
  const int which = idx >> 18;
  const int rr = idx & 262143;
  const float* w = (which == 0) ? wq : (which == 1) ? wk : (which == 2) ? wv : wo;
  const int n = rr >> 9, k = rr & 511;
  wT[idx] = f2bf(w[k * 512 + n]);
}

#define GEMM_STAGE(buf, t)                                                       \
  {                                                                              \
    const int k0 = (t) * 32;                                                     \
    _Pragma("unroll")                                                            \
    for (int i = 0; i < 2; ++i) {                                                \
      const int cid = tid + i * 256;                                             \
      const int row = cid >> 2, cb = cid & 3;                                    \
      const int sc = (cb ^ (row & 3)) << 3;                                      \
      gload16(A + (size_t)(brow + row) * 512 + k0 + sc, &lA[buf][cid << 3]);     \
      gload16(Bt + (size_t)(bcol0 + row) * 512 + k0 + sc, &lB[buf][cid << 3]);   \
    }                                                                            \
  }

#define GEMM_MAIN                                                                \
  const f32x4 zero4 = {0.f, 0.f, 0.f, 0.f};                                      \
  f32x4 acc[4][4];                                                               \
  _Pragma("unroll") for (int a_ = 0; a_ < 4; ++a_)                               \
  _Pragma("unroll") for (int b_ = 0; b_ < 4; ++b_) acc[a_][b_] = zero4;          \
  GEMM_STAGE(0, 0);                                                              \
  asm volatile("s_waitcnt vmcnt(0)" ::: "memory");                               \
  __syncthreads();                                                               \
  int buf = 0;                                                                   \
  for (int t = 0; t < 16; ++t) {                                                 \
    if (t < 15) GEMM_STAGE(buf ^ 1, t + 1);                                      \
    bf16x8 af[4], bfv[4];                                                        \
    _Pragma("unroll") for (int f = 0; f < 4; ++f) {                              \
      const int ra = wr * 64 + f * 16 + l15;                                     \
      af[f] = *(const bf16x8*)(&lA[buf][(ra << 5) + ((lq ^ (ra & 3)) << 3)]);    \
      const int rb = wc * 64 + f * 16 + l15;                                     \
      bfv[f] = *(const bf16x8*)(&lB[buf][(rb << 5) + ((lq ^ (rb & 3)) << 3)]);   \
    }                                                                            \
    _Pragma("unroll") for (int fa = 0; fa < 4; ++fa)                             \
    _Pragma("unroll") for (int fb = 0; fb < 4; ++fb)                             \
      acc[fa][fb] = __builtin_amdgcn_mfma_f32_16x16x32_bf16(af[fa], bfv[fb],     \
                                                            acc[fa][fb], 0, 0, 0);\
    asm volatile("s_waitcnt vmcnt(0)" ::: "memory");                             \
    __syncthreads();                                                             \
    buf ^= 1;                                                                    \
  }

// ---------------- o-projection GEMM: f32 out, +bias +residual ----------------
__global__ __launch_bounds__(256)
void gemm_oproj(const u16* __restrict__ A, const u16* __restrict__ Bt,
                const float* __restrict__ bias, const float* __restrict__ resid,
                float* __restrict__ Cout) {
  const int tid = threadIdx.x;
  const int wid = tid >> 6, l = tid & 63;
  const int wr = wid >> 1, wc = wid & 1;
  const int l15 = l & 15, lq = l >> 4;
  const int brow = blockIdx.x * 128, bcol0 = blockIdx.y * 128;
  __shared__ u16 lA[2][4096];
  __shared__ u16 lB[2][4096];
  GEMM_MAIN
#pragma unroll
  for (int fa = 0; fa < 4; ++fa)
#pragma unroll
    for (int fb = 0; fb < 4; ++fb) {
      const int col = bcol0 + wc * 64 + fb * 16 + l15;
      const float bv = bias[col];
#pragma unroll
      for (int i = 0; i < 4; ++i) {
        const int row = brow + wr * 64 + fa * 16 + lq * 4 + i;
        const size_t idx = (size_t)row * 512 + col;
        Cout[idx] = acc[fa][fb][i] + bv + resid[idx];
      }
    }
}

// ---------------- fused QKV GEMM: grid (128, 12) ----------------
__global__ __launch_bounds__(256)
void gemm_qkv(const u16* __restrict__ A, const u16* __restrict__ wT,
              const float* __restrict__ bq, const float* __restrict__ bk,
              const float* __restrict__ bv_, u16* __restrict__ q,
              u16* __restrict__ k, u16* __restrict__ v8, float qs) {
  const int tid = threadIdx.x;
  const int wid = tid >> 6, l = tid & 63;
  const int wr = wid >> 1, wc = wid & 1;
  const int l15 = l & 15, lq = l >> 4;
  const int which = blockIdx.y >> 2;
  const int brow = blockIdx.x * 128, bcol0 = (blockIdx.y & 3) * 128;
  const u16* Bt = wT + which * 262144;
  const float* bias = (which == 0) ? bq : ((which == 1) ? bk : bv_);
  __shared__ u16 lA[2][4096];
  __shared__ u16 lB[2][4096];
  GEMM_MAIN
#pragma unroll
  for (int fa = 0; fa < 4; ++fa)
#pragma unroll
    for (int fb = 0; fb < 4; ++fb) {
      const int col = bcol0 + wc * 64 + fb * 16 + l15;
      const float bb_ = bias[col];
#pragma unroll
      for (int i = 0; i < 4; ++i) {
        const int row = brow + wr * 64 + fa * 16 + lq * 4 + i;
        const float v = acc[fa][fb][i] + bb_;
        if (which == 0) {
          q[(size_t)row * 512 + col] = f2bf(v * qs);
        } else if (which == 1) {
          k[(size_t)row * 512 + col] = f2bf(v);
        } else {
          const int bb = row >> 12, n = row & 4095;
          // V8 layout with nb-XOR bank swizzle baked in (chunk index ^= block&3)
          v8[((size_t)(bb * 512 + (n >> 3))) * 4096 +
             (size_t)((col ^ ((n >> 3) & 3)) << 3) + (n & 7)] = f2bf(v);
        }
      }
    }
}

// ---------------- flash attention v6: swapped QK^T, wave-private softmax -----
// grid 256 (b = bid&3 for XCD/L2 locality), block 512 = 4 q-groups x 2 d-halves.
// Per step (32 kv): barrier A (staged ready) -> partial S^T = mfma(K,Q) over
// 256-d half -> Sp exchange -> barrier B -> [wave-private: add partner partial,
// in-lane softmax, 8-shfl P transpose, PV]. No Sb/Pb, softmax overlaps PV.
__global__ __launch_bounds__(512)
void attn_kernel(const u16* __restrict__ Q, const u16* __restrict__ K,
                 const u16* __restrict__ V8, u16* __restrict__ Oo) {
  const int bid = blockIdx.x;
  const int b = bid & 3, qb = bid >> 2;  // same-batch blocks share an XCD
  const int tid = threadIdx.x;
  const int wid = tid >> 6, l = tid & 63;
  const int h = wid & 1;     // d-half (256 cols)
  const int r = wid >> 1;    // q-group (16 rows)
  const int l15 = l & 15, lq = l >> 4;

  __shared__ u16 Kl[2][16384];     // 2 x 32 KB K tile [32][512], chunk-XOR swizzled
  __shared__ u16 Vl[2][16384];     // 2 x 32 KB V tile, blocked [4][512][8] + baked swz
  __shared__ float Sp[8][8][64];   // 16 KB partial-S exchange, SoA conflict-free

  const u16* Kb = K + (size_t)b * 2097152;
  const u16* Vb = V8 + (size_t)b * 2097152;

#define STAGEK(tt)                                                     \
  {                                                                    \
    const u16* ks = Kb + (size_t)((tt) & 127) * 16384;                 \
    char* kd = (char*)(&Kl[(tt) & 1][0]);                              \
    _Pragma("unroll") for (int i = 0; i < 4; ++i) {                    \
      const int cid = tid + i * 512;                                   \
      const int ob = cid << 4;                                         \
      const int n_ = ob >> 10;                                         \
      const int cb = (ob & 1023) ^ ((n_ & 7) << 4);                    \
      gload16(ks + (size_t)n_ * 512 + (cb >> 1), kd + ob);             \
    }                                                                  \
  }
#define STAGEV(tt)                                                     \
  {                                                                    \
    const u16* vs = Vb + (size_t)((tt) & 127) * 16384;                 \
    char* vd = (char*)(&Vl[(tt) & 1][0]);                              \
    _Pragma("unroll") for (int i = 0; i < 4; ++i) {                    \
      const int cid = tid + i * 512;                                   \
      gload16(vs + (cid << 3), vd + (cid << 4));                       \
    }                                                                  \
  }

  STAGEK(0); STAGEV(0);

  // Q fragments (B-operand: col=q=l15, k=lq*8): rows r*16..+16, d-half h (32 VGPR)
  bf16x8 qf[8];
  {
    const u16* qp = Q + ((size_t)(b * 4096 + qb * 64 + r * 16 + l15)) * 512 + h * 256 + lq * 8;
#pragma unroll
    for (int kk = 0; kk < 8; ++kk) qf[kk] = *(const bf16x8*)(qp + kk * 32);
  }
  const f32x4 zero4 = {0.f, 0.f, 0.f, 0.f};
  f32x4 o[16];  // O[16q][256d]: tile f -> d h*256+f*16+l15, row q = lq*4+i
#pragma unroll
  for (int f = 0; f < 16; ++f) o[f] = zero4;
  float m_ = -3e38f, l_ = 0.f;

  const int kswz = (l15 & 7) << 4;
  const int slot = wid, pslot = wid ^ 1;  // partner = other d-half, same r

  for (int t = 0; t < 128; ++t) {
    vmwait<0>();
    barrier_lgkm();          // A: K/V(t) staged; Sp(t-1) fully consumed
    STAGEK(t + 1);
    STAGEV(t + 1);

    // ---- partial S^T = mfma(K, Q) over this wave's 256-d half ----
    const char* kb = (const char*)(&Kl[t & 1][0]);
    f32x4 s0 = zero4, s1 = zero4;
    {
      const char* row0 = kb + l15 * 1024;          // kv tile 0: rows l15
      const char* row1 = kb + (16 + l15) * 1024;   // kv tile 1: rows 16+l15
#pragma unroll
      for (int kk = 0; kk < 8; ++kk) {
        const int off = (h * 512 + kk * 64 + lq * 16) ^ kswz;
        const bf16x8 k0 = *(const bf16x8*)(row0 + off);
        s0 = __builtin_amdgcn_mfma_f32_16x16x32_bf16(k0, qf[kk], s0, 0, 0, 0);
        const bf16x8 k1 = *(const bf16x8*)(row1 + off);
        s1 = __builtin_amdgcn_mfma_f32_16x16x32_bf16(k1, qf[kk], s1, 0, 0, 0);
      }
    }
    {
      float* sp = &Sp[slot][0][l];
#pragma unroll
      for (int e = 0; e < 4; ++e) { sp[e * 64] = s0[e]; sp[(4 + e) * 64] = s1[e]; }
    }
    barrier_lgkm();          // B: partials visible

    // ---- wave-private: combine partner partial + in-lane softmax ----
    float p_[8];
    {
      const float* pp = &Sp[pslot][0][l];
#pragma unroll
      for (int e = 0; e < 4; ++e) {
        p_[e] = s0[e] + pp[e * 64];
        p_[4 + e] = s1[e] + pp[(4 + e) * 64];
      }
    }
    float tmax = fmaxf(fmaxf(fmaxf(p_[0], p_[1]), fmaxf(p_[2], p_[3])),
                       fmaxf(fmaxf(p_[4], p_[5]), fmaxf(p_[6], p_[7])));
    tmax = fmaxf(tmax, __shfl_xor(tmax, 16));
    tmax = fmaxf(tmax, __shfl_xor(tmax, 32));
    const bool need = tmax > m_ + 8.0f;
    const float mn = need ? tmax : m_;
    const float al = need ? __expf(m_ - mn) : 1.0f;
#pragma unroll
    for (int e = 0; e < 8; ++e) p_[e] = __expf(p_[e] - mn);
    float ps = ((p_[0] + p_[1]) + (p_[2] + p_[3])) + ((p_[4] + p_[5]) + (p_[6] + p_[7]));
    ps += __shfl_xor(ps, 16);
    ps += __shfl_xor(ps, 32);
    l_ = l_ * al + ps;
    m_ = mn;

    // ---- P^T -> A-frag transpose via 8 shuffles ----
    // lane holds P[q=l15][kv=s2*16+lq*4+i]; A-frag needs P[q=l15][kv=lq*8..+8]
    int pk[2][2];
#pragma unroll
    for (int s2 = 0; s2 < 2; ++s2)
#pragma unroll
      for (int j = 0; j < 2; ++j)
        pk[s2][j] = (int)((unsigned)f2bf(p_[s2 * 4 + 2 * j]) |
                          ((unsigned)f2bf(p_[s2 * 4 + 2 * j + 1]) << 16));
    const int srcb = ((lq & 1) << 5) + l15;  // (2*(lq&1))*16 + l15
    int tp[2][2][2];
#pragma unroll
    for (int s2 = 0; s2 < 2; ++s2)
#pragma unroll
      for (int j = 0; j < 2; ++j) {
        tp[s2][j][0] = __shfl(pk[s2][j], srcb);
        tp[s2][j][1] = __shfl(pk[s2][j], srcb + 16);
      }
    const bool hi2 = (lq >> 1) != 0;
    i32x4 pv;
    pv[0] = hi2 ? tp[1][0][0] : tp[0][0][0];
    pv[1] = hi2 ? tp[1][1][0] : tp[0][1][0];
    pv[2] = hi2 ? tp[1][0][1] : tp[0][0][1];
    pv[3] = hi2 ? tp[1][1][1] : tp[0][1][1];
    const bf16x8 pa = __builtin_bit_cast(bf16x8, pv);

    // ---- rescale O (rare, defer-max) ----
    if (__any(need)) {
      float aq[4];
#pragma unroll
      for (int i = 0; i < 4; ++i) aq[i] = __shfl(al, lq * 4 + i);
#pragma unroll
      for (int f = 0; f < 16; ++f) {
        o[f][0] *= aq[0]; o[f][1] *= aq[1]; o[f][2] *= aq[2]; o[f][3] *= aq[3];
      }
    }

    // ---- O += P V (wave-private; V cols h*256..+256) ----
    {
      const char* vbase = (const char*)(&Vl[t & 1][0]) + (lq << 13);
#pragma unroll
      for (int f = 0; f < 16; ++f) {
        const int ci = (h * 256 + f * 16 + l15) ^ lq;  // baked bank swizzle
        const bf16x8 vf = *(const bf16x8*)(vbase + (ci << 4));
        o[f] = __builtin_amdgcn_mfma_f32_16x16x32_bf16(pa, vf, o[f], 0, 0, 0);
      }
    }
  }
#undef STAGEK
#undef STAGEV

  // ---- epilogue: O /= l, cast bf16, store (disjoint per wave) ----
  {
    float li[4];
#pragma unroll
    for (int i = 0; i < 4; ++i) li[i] = 1.0f / __shfl(l_, lq * 4 + i);
    u16* ob = Oo + ((size_t)(b * 4096 + qb * 64 + r * 16)) * 512 + h * 256;
#pragma unroll
    for (int f = 0; f < 16; ++f) {
      const int col = f * 16 + l15;
#pragma unroll
      for (int i = 0; i < 4; ++i)
        ob[(size_t)(lq * 4 + i) * 512 + col] = f2bf(o[f][i] * li[i]);
    }
  }
}

extern "C" void kernel_launch(void* const* d_in, const int* in_sizes, int n_in,
                              void* d_out, int out_size, void* d_ws, size_t ws_size,
                              hipStream_t stream) {
  const float* x     = (const float*)d_in[0];
  const float* gamma = (const float*)d_in[1];
  const float* beta  = (const float*)d_in[2];
  const float* wq    = (const float*)d_in[3];
  const float* bq    = (const float*)d_in[4];
  const float* wk    = (const float*)d_in[5];
  const float* bk    = (const float*)d_in[6];
  const float* wv    = (const float*)d_in[7];
  const float* bv    = (const float*)d_in[8];
  const float* wo    = (const float*)d_in[9];
  const float* bo    = (const float*)d_in[10];
  float* out = (float*)d_out;

  char* ws = (char*)d_ws;
  const size_t SZ = (size_t)16384 * 512;
  u16* h    = (u16*)(ws);                 // 16 MB
  u16* q    = (u16*)(ws + SZ * 2);        // 16 MB (pre-scaled by C^-0.5)
  u16* k    = (u16*)(ws + SZ * 4);        // 16 MB
  u16* v8   = (u16*)(ws + SZ * 6);        // 16 MB, [B][N/8][C^(blk&3)][8]
  u16* aout = (u16*)(ws + SZ * 8);        // 16 MB
  u16* wT   = (u16*)(ws + SZ * 10);       // 4 x 512KB
  float* part  = (float*)(ws + SZ * 10 + 4 * 262144 * 2);
  float* stats = part + 2048;

  gn_partial<<<dim3(8, 32, 4), 256, 0, stream>>>(x, part);
  gn_finalize<<<1, 128, 0, stream>>>(part, stats);
  gn_apply<<<8192, 256, 0, stream>>>(x, gamma, beta, stats, h);

  wcast_t4<<<4096, 256, 0, stream>>>(wq, wk, wv, wo, wT);

  const float qs = 0.044194173824159216f;  // 512^-0.5
  gemm_qkv<<<dim3(128, 12), 256, 0, stream>>>(h, wT, bq, bk, bv, q, k, v8, qs);

  attn_kernel<<<256, 512, 0, stream>>>(q, k, v8, aout);

  gemm_oproj<<<dim3(128, 4), 256, 0, stream>>>(aout, wT + 3 * 262144, bo, x, out);
}

// Round 7
// 259.415 us; speedup vs baseline: 4.4877x; 1.5203x over previous
//
#include <hip/hip_runtime.h>

typedef __bf16 bf16x8 __attribute__((ext_vector_type(8)));
typedef float  f32x4  __attribute__((ext_vector_type(4)));
typedef float  f32x16 __attribute__((ext_vector_type(16)));
typedef unsigned long long u64x2 __attribute__((ext_vector_type(2)));
typedef unsigned short u16;
typedef unsigned short us4 __attribute__((ext_vector_type(4)));

__device__ __forceinline__ u16 f2bf(float f) {
  __bf16 h = (__bf16)f;
  return __builtin_bit_cast(u16, h);
}

__device__ __forceinline__ void gload16(const void* g, void* l) {
  __builtin_amdgcn_global_load_lds(
      (const __attribute__((address_space(1))) unsigned int*)(g),
      (__attribute__((address_space(3))) unsigned int*)(l), 16, 0, 0);
}

__device__ __forceinline__ void barrier_lgkm() {
  asm volatile("s_waitcnt lgkmcnt(0)" ::: "memory");
  __builtin_amdgcn_s_barrier();
  asm volatile("" ::: "memory");
}
template <int N> __device__ __forceinline__ void vmwait() {
  asm volatile("s_waitcnt vmcnt(%0)" :: "n"(N) : "memory");
}

// ---------------- GroupNorm: pass 1 (partial sums) ----------------
__global__ void gn_partial(const float* __restrict__ x, float* __restrict__ part) {
  const int chunk = blockIdx.x, g = blockIdx.y, b = blockIdx.z;
  const int tid = threadIdx.x;
  float s = 0.f, ss = 0.f;
  const float* xb = x + ((size_t)(b * 4096 + chunk * 512)) * 512 + g * 16;
  for (int i = tid; i < 2048; i += 256) {
    const int sp = i >> 2, c4 = (i & 3) << 2;
    const float4 v = *(const float4*)(xb + (size_t)sp * 512 + c4);
    s  += v.x + v.y + v.z + v.w;
    ss += v.x * v.x + v.y * v.y + v.z * v.z + v.w * v.w;
  }
  for (int m = 32; m; m >>= 1) { s += __shfl_xor(s, m); ss += __shfl_xor(ss, m); }
  __shared__ float red[8];
  const int w = tid >> 6;
  if ((tid & 63) == 0) { red[w * 2] = s; red[w * 2 + 1] = ss; }
  __syncthreads();
  if (tid == 0) {
    float S = 0.f, SS = 0.f;
    for (int i = 0; i < 4; ++i) { S += red[2 * i]; SS += red[2 * i + 1]; }
    const int idx = ((b * 32 + g) * 8 + chunk) * 2;
    part[idx] = S; part[idx + 1] = SS;
  }
}

// ---------------- GroupNorm: pass 2 (finalize) ----------------
__global__ void gn_finalize(const float* __restrict__ part, float* __restrict__ stats) {
  const int t = threadIdx.x;  // 128 = 4*32
  if (t < 128) {
    float S = 0.f, SS = 0.f;
    for (int i = 0; i < 8; ++i) { S += part[(t * 8 + i) * 2]; SS += part[(t * 8 + i) * 2 + 1]; }
    const float mean = S * (1.0f / 65536.0f);
    const float var  = SS * (1.0f / 65536.0f) - mean * mean;
    stats[t * 2] = mean;
    stats[t * 2 + 1] = rsqrtf(var + 1e-6f);
  }
}

// ---------------- GroupNorm: pass 3 (normalize + cast bf16) ----------------
__global__ void gn_apply(const float* __restrict__ x, const float* __restrict__ gamma,
                         const float* __restrict__ beta, const float* __restrict__ stats,
                         u16* __restrict__ h) {
  const size_t i = (size_t)blockIdx.x * 256 + threadIdx.x;
  const size_t e = i * 4;
  const int c = (int)(e & 511);
  const int b = (int)(e >> 21);
  const int g = c >> 4;
  const float mean = stats[(b * 32 + g) * 2];
  const float rstd = stats[(b * 32 + g) * 2 + 1];
  const float4 xv = *(const float4*)(x + e);
  const float4 gv = *(const float4*)(gamma + c);
  const float4 bv = *(const float4*)(beta + c);
  us4 hv;
  hv.x = f2bf((xv.x - mean) * rstd * gv.x + bv.x);
  hv.y = f2bf((xv.y - mean) * rstd * gv.y + bv.y);
  hv.z = f2bf((xv.z - mean) * rstd * gv.z + bv.z);
  hv.w = f2bf((xv.w - mean) * rstd * gv.w + bv.w);
  *(us4*)(h + e) = hv;
}

// ---------------- fused weight transpose + cast (all 4 weights) ----------------
__global__ void wcast_t4(const float* __restrict__ wq, const float* __restrict__ wk,
                         const float* __restrict__ wv, const float* __restrict__ wo,
                         u16* __restrict__ wT) {
  const int idx = blockIdx.x * 256 + threadIdx.x;  // 0..1048575
  const int which = idx >> 18;
  const int rr = idx & 262143;
  const float* w = (which == 0) ? wq : (which == 1) ? wk : (which == 2) ? wv : wo;
  const int n = rr >> 9, k = rr & 511;
  wT[idx] = f2bf(w[k * 512 + n]);
}

#define GEMM_STAGE(buf, t)                                                       \
  {                                                                              \
    const int k0 = (t) * 32;                                                     \
    _Pragma("unroll")                                                            \
    for (int i = 0; i < 2; ++i) {                                                \
      const int cid = tid + i * 256;                                             \
      const int row = cid >> 2, cb = cid & 3;                                    \
      const int sc = (cb ^ (row & 3)) << 3;                                      \
      gload16(A + (size_t)(brow + row) * 512 + k0 + sc, &lA[buf][cid << 3]);     \
      gload16(Bt + (size_t)(bcol0 + row) * 512 + k0 + sc, &lB[buf][cid << 3]);   \
    }                                                                            \
  }

#define GEMM_MAIN                                                                \
  const f32x4 zero4 = {0.f, 0.f, 0.f, 0.f};                                      \
  f32x4 acc[4][4];                                                               \
  _Pragma("unroll") for (int a_ = 0; a_ < 4; ++a_)                               \
  _Pragma("unroll") for (int b_ = 0; b_ < 4; ++b_) acc[a_][b_] = zero4;          \
  GEMM_STAGE(0, 0);                                                              \
  asm volatile("s_waitcnt vmcnt(0)" ::: "memory");                               \
  __syncthreads();                                                               \
  int buf = 0;                                                                   \
  for (int t = 0; t < 16; ++t) {                                                 \
    if (t < 15) GEMM_STAGE(buf ^ 1, t + 1);                                      \
    bf16x8 af[4], bfv[4];                                                        \
    _Pragma("unroll") for (int f = 0; f < 4; ++f) {                              \
      const int ra = wr * 64 + f * 16 + l15;                                     \
      af[f] = *(const bf16x8*)(&lA[buf][(ra << 5) + ((lq ^ (ra & 3)) << 3)]);    \
      const int rb = wc * 64 + f * 16 + l15;                                     \
      bfv[f] = *(const bf16x8*)(&lB[buf][(rb << 5) + ((lq ^ (rb & 3)) << 3)]);   \
    }                                                                            \
    _Pragma("unroll") for (int fa = 0; fa < 4; ++fa)                             \
    _Pragma("unroll") for (int fb = 0; fb < 4; ++fb)                             \
      acc[fa][fb] = __builtin_amdgcn_mfma_f32_16x16x32_bf16(af[fa], bfv[fb],     \
                                                            acc[fa][fb], 0, 0, 0);\
    asm volatile("s_waitcnt vmcnt(0)" ::: "memory");                             \
    __syncthreads();                                                             \
    buf ^= 1;                                                                    \
  }

// ---------------- o-projection GEMM: f32 out, +bias +residual ----------------
__global__ __launch_bounds__(256)
void gemm_oproj(const u16* __restrict__ A, const u16* __restrict__ Bt,
                const float* __restrict__ bias, const float* __restrict__ resid,
                float* __restrict__ Cout) {
  const int tid = threadIdx.x;
  const int wid = tid >> 6, l = tid & 63;
  const int wr = wid >> 1, wc = wid & 1;
  const int l15 = l & 15, lq = l >> 4;
  const int brow = blockIdx.x * 128, bcol0 = blockIdx.y * 128;
  __shared__ u16 lA[2][4096];
  __shared__ u16 lB[2][4096];
  GEMM_MAIN
#pragma unroll
  for (int fa = 0; fa < 4; ++fa)
#pragma unroll
    for (int fb = 0; fb < 4; ++fb) {
      const int col = bcol0 + wc * 64 + fb * 16 + l15;
      const float bv = bias[col];
#pragma unroll
      for (int i = 0; i < 4; ++i) {
        const int row = brow + wr * 64 + fa * 16 + lq * 4 + i;
        const size_t idx = (size_t)row * 512 + col;
        Cout[idx] = acc[fa][fb][i] + bv + resid[idx];
      }
    }
}

// ---------------- fused QKV GEMM: grid (128, 12) ----------------
__global__ __launch_bounds__(256)
void gemm_qkv(const u16* __restrict__ A, const u16* __restrict__ wT,
              const float* __restrict__ bq, const float* __restrict__ bk,
              const float* __restrict__ bv_, u16* __restrict__ q,
              u16* __restrict__ k, u16* __restrict__ v8, float qs) {
  const int tid = threadIdx.x;
  const int wid = tid >> 6, l = tid & 63;
  const int wr = wid >> 1, wc = wid & 1;
  const int l15 = l & 15, lq = l >> 4;
  const int which = blockIdx.y >> 2;
  const int brow = blockIdx.x * 128, bcol0 = (blockIdx.y & 3) * 128;
  const u16* Bt = wT + which * 262144;
  const float* bias = (which == 0) ? bq : ((which == 1) ? bk : bv_);
  __shared__ u16 lA[2][4096];
  __shared__ u16 lB[2][4096];
  GEMM_MAIN
#pragma unroll
  for (int fa = 0; fa < 4; ++fa)
#pragma unroll
    for (int fb = 0; fb < 4; ++fb) {
      const int col = bcol0 + wc * 64 + fb * 16 + l15;
      const float bb_ = bias[col];
#pragma unroll
      for (int i = 0; i < 4; ++i) {
        const int row = brow + wr * 64 + fa * 16 + lq * 4 + i;
        const float v = acc[fa][fb][i] + bb_;
        if (which == 0) {
          q[(size_t)row * 512 + col] = f2bf(v * qs);
        } else if (which == 1) {
          k[(size_t)row * 512 + col] = f2bf(v);
        } else {
          const int bb = row >> 12, n = row & 4095;
          // V8 layout with chunk-XOR bank swizzle baked in (col ^= block&3)
          v8[((size_t)(bb * 512 + (n >> 3))) * 4096 +
             (size_t)((col ^ ((n >> 3) & 3)) << 3) + (n & 7)] = f2bf(v);
        }
      }
    }
}

// ---------------- flash attention v7: wave-specialized, 32x32 MFMA -----------
// grid 256 (b = bid&3 -> XCD locality), block 512 = 8 waves:
//   wid 0,1  = S-waves  (qh = wid): S^T[32kv][32q] = mfma32(K, Q), full D,
//              in-lane softmax (col=q layout), write P bf16 + a + flag.
//   wid 2..5 = PV-waves (dq = wid-2): O[64q][128d] += P(t-1) V(t-1), 32x32 MFMA.
//   wid 6,7  = staging waves: all global_load_lds + vmcnt waits.
// One barrier per 32-kv step. K read 2x/step, V read 1x/step.
__global__ __launch_bounds__(512, 2)
void attn_kernel(const u16* __restrict__ Q, const u16* __restrict__ K,
                 const u16* __restrict__ V8, u16* __restrict__ Oo) {
  const int bid = blockIdx.x;
  const int b = bid & 3, qb = bid >> 2;
  const int tid = threadIdx.x;
  const int wid = tid >> 6, l = tid & 63;
  const int l31 = l & 31, lh = l >> 5;

  // LDS layout (bytes):
  //   Kl[2]  @ 0      : 2 x 32768   (K tile [32][512] bf16, chunk^(row&15) swizzle)
  //   Vl[2]  @ 65536  : 2 x 32768   (V tile v8-blocked [4][512^c4][8])
  //   Pb[2]  @ 131072 : 2 x 4608    (P bf16 [64 rows][stride 72 B])
  //   abuf[2]@ 140288 : 2 x 256     (rescale factors f32[64])
  //   flags  @ 140800 : 2 x 2 x 4
  //   lrow   @ 140816 : 64 x 4
  __shared__ __align__(16) char lds[141072];
  const int PB = 131072, AB = 140288, FL = 140800, LR = 140816;

  const u16* Kb = K + (size_t)b * 2097152;
  const u16* Vb = V8 + (size_t)b * 2097152;

  const f32x16 z16 = {0.f,0.f,0.f,0.f, 0.f,0.f,0.f,0.f, 0.f,0.f,0.f,0.f, 0.f,0.f,0.f,0.f};

  if (wid >= 6) {
    // =================== staging waves ===================
    const int stid = (wid - 6) * 64 + l;
    // prologue: K(0)
    {
      char* kd = lds;
#pragma unroll
      for (int i = 0; i < 16; ++i) {
        const int cid = stid + i * 128;
        const int ob = cid << 4;
        const int n_ = ob >> 10;
        const int cb = (ob & 1023) ^ ((n_ & 15) << 4);
        gload16(Kb + (size_t)n_ * 512 + (cb >> 1), kd + ob);
      }
    }
    vmwait<0>();
    barrier_lgkm();                       // #0
    for (int t = 0; t < 128; ++t) {
      if (t < 127) {                      // K(t+1) -> Kl[(t+1)&1]
        const u16* ks = Kb + (size_t)(t + 1) * 16384;
        char* kd = lds + (((t + 1) & 1) << 15);
#pragma unroll
        for (int i = 0; i < 16; ++i) {
          const int cid = stid + i * 128;
          const int ob = cid << 4;
          const int n_ = ob >> 10;
          const int cb = (ob & 1023) ^ ((n_ & 15) << 4);
          gload16(ks + (size_t)n_ * 512 + (cb >> 1), kd + ob);
        }
      }
      {                                   // V(t) -> Vl[t&1]
        const u16* vs = Vb + (size_t)t * 16384;
        char* vd = lds + 65536 + ((t & 1) << 15);
#pragma unroll
        for (int i = 0; i < 16; ++i) {
          const int cid = stid + i * 128;
          gload16(vs + (size_t)cid * 8, vd + (cid << 4));
        }
      }
      vmwait<0>();
      barrier_lgkm();
    }
    barrier_lgkm();                       // epilogue sync
  } else if (wid < 2) {
    // =================== S-waves ===================
    const int qh = wid;
    barrier_lgkm();                       // #0
    // Q fragments (B-operand): col=q=l31, k-chunk lh*8; rows qh*32..+32
    bf16x8 qf[32];
    {
      const u16* qp = Q + ((size_t)(b * 4096 + qb * 64 + qh * 32 + l31)) * 512 + lh * 8;
#pragma unroll
      for (int kk = 0; kk < 32; ++kk) qf[kk] = *(const bf16x8*)(qp + kk * 16);
    }
    float m_ = -3e38f, l_ = 0.f;
    const int kxor = (l31 & 15) << 4;
    for (int t = 0; t < 128; ++t) {
      const char* kb = lds + ((t & 1) << 15) + l31 * 1024;
      f32x16 a0 = z16, a1 = z16;
#pragma unroll
      for (int kk = 0; kk < 32; kk += 2) {
        const bf16x8 k0 = *(const bf16x8*)(kb + ((kk * 32 + lh * 16) ^ kxor));
        a0 = __builtin_amdgcn_mfma_f32_32x32x16_bf16(k0, qf[kk], a0, 0, 0, 0);
        const bf16x8 k1 = *(const bf16x8*)(kb + (((kk + 1) * 32 + lh * 16) ^ kxor));
        a1 = __builtin_amdgcn_mfma_f32_32x32x16_bf16(k1, qf[kk + 1], a1, 0, 0, 0);
      }
      const f32x16 s = a0 + a1;
      // in-lane softmax: lane col = q, 16 kv values here + 16 in lane^32
      float tmax = fmaxf(s[0], s[1]);
#pragma unroll
      for (int r2 = 2; r2 < 16; ++r2) tmax = fmaxf(tmax, s[r2]);
      tmax = fmaxf(tmax, __shfl_xor(tmax, 32));
      const bool need = tmax > m_ + 8.0f;
      const float mn = need ? tmax : m_;
      const float al = need ? __expf(m_ - mn) : 1.0f;
      float p[16];
#pragma unroll
      for (int r2 = 0; r2 < 16; ++r2) p[r2] = __expf(s[r2] - mn);
      float ps = 0.f;
#pragma unroll
      for (int r2 = 0; r2 < 16; ++r2) ps += p[r2];
      ps += __shfl_xor(ps, 32);
      l_ = l_ * al + ps;
      m_ = mn;
      // write P: kv(reg) = (reg&3) + 8*(reg>>2) + 4*lh -> rows of A-frag
      char* prow = lds + PB + (t & 1) * 4608 + (qh * 32 + l31) * 72;
#pragma unroll
      for (int rg = 0; rg < 4; ++rg) {
        us4 pk4;
        pk4.x = f2bf(p[rg * 4 + 0]); pk4.y = f2bf(p[rg * 4 + 1]);
        pk4.z = f2bf(p[rg * 4 + 2]); pk4.w = f2bf(p[rg * 4 + 3]);
        *(unsigned long long*)(prow + rg * 16 + lh * 8) =
            __builtin_bit_cast(unsigned long long, pk4);
      }
      if (lh == 0) *(float*)(lds + AB + (t & 1) * 256 + (qh * 32 + l31) * 4) = al;
      const bool anyn = __any(need);
      if (l == 0) *(int*)(lds + FL + ((t & 1) * 2 + qh) * 4) = anyn ? 1 : 0;
      barrier_lgkm();
    }
    if (lh == 0) *(float*)(lds + LR + (qh * 32 + l31) * 4) = l_;
    barrier_lgkm();                       // epilogue sync
  } else {
    // =================== PV-waves ===================
    const int dq = wid - 2;
    barrier_lgkm();                       // #0
    f32x16 o[2][4];
#pragma unroll
    for (int qt = 0; qt < 2; ++qt)
#pragma unroll
      for (int f = 0; f < 4; ++f) o[qt][f] = z16;

    auto pv_apply = [&](int pb_) {
      // P A-frags: row=q=l31(+qt*32), k-chunk kv = h2*16 + lh*8 ..+8
      bf16x8 pa[2][2];
#pragma unroll
      for (int qt = 0; qt < 2; ++qt)
#pragma unroll
        for (int h2 = 0; h2 < 2; ++h2) {
          const char* pr = lds + PB + pb_ * 4608 + (qt * 32 + l31) * 72 + h2 * 32 + lh * 16;
          u64x2 w2;
          w2[0] = *(const unsigned long long*)pr;
          w2[1] = *(const unsigned long long*)(pr + 8);
          pa[qt][h2] = __builtin_bit_cast(bf16x8, w2);
        }
      const int fl = *(const int*)(lds + FL + pb_ * 8) |
                     *(const int*)(lds + FL + pb_ * 8 + 4);
      if (fl) {
#pragma unroll
        for (int qt = 0; qt < 2; ++qt)
#pragma unroll
          for (int rg = 0; rg < 16; ++rg) {
            const int cr = (rg & 3) + 8 * (rg >> 2) + 4 * lh;
            const float av = *(const float*)(lds + AB + pb_ * 256 + (qt * 32 + cr) * 4);
#pragma unroll
            for (int f = 0; f < 4; ++f) o[qt][f][rg] *= av;
          }
      }
      const char* vb = lds + 65536 + (pb_ << 15);
#pragma unroll
      for (int f = 0; f < 4; ++f) {
        const int d = dq * 128 + f * 32 + l31;
#pragma unroll
        for (int h2 = 0; h2 < 2; ++h2) {
          const int c4 = h2 * 2 + lh;
          const bf16x8 vf = *(const bf16x8*)(vb + (size_t)(c4 * 512 + (d ^ c4)) * 16);
          o[0][f] = __builtin_amdgcn_mfma_f32_32x32x16_bf16(pa[0][h2], vf, o[0][f], 0, 0, 0);
          o[1][f] = __builtin_amdgcn_mfma_f32_32x32x16_bf16(pa[1][h2], vf, o[1][f], 0, 0, 0);
        }
      }
    };

    for (int t = 0; t < 128; ++t) {
      if (t > 0) pv_apply((t - 1) & 1);
      barrier_lgkm();
    }
    pv_apply(1);                          // P(127), V(127)
    barrier_lgkm();                       // epilogue sync (lrow published)
    // epilogue: O /= l, store bf16
#pragma unroll
    for (int qt = 0; qt < 2; ++qt)
#pragma unroll
      for (int rg = 0; rg < 16; ++rg) {
        const int cr = (rg & 3) + 8 * (rg >> 2) + 4 * lh;
        const float li = 1.0f / *(const float*)(lds + LR + (qt * 32 + cr) * 4);
        u16* orow = Oo + ((size_t)(b * 4096 + qb * 64 + qt * 32 + cr)) * 512 + dq * 128 + l31;
#pragma unroll
        for (int f = 0; f < 4; ++f) orow[f * 32] = f2bf(o[qt][f][rg] * li);
      }
  }
}

extern "C" void kernel_launch(void* const* d_in, const int* in_sizes, int n_in,
                              void* d_out, int out_size, void* d_ws, size_t ws_size,
                              hipStream_t stream) {
  const float* x     = (const float*)d_in[0];
  const float* gamma = (const float*)d_in[1];
  const float* beta  = (const float*)d_in[2];
  const float* wq    = (const float*)d_in[3];
  const float* bq    = (const float*)d_in[4];
  const float* wk    = (const float*)d_in[5];
  const float* bk    = (const float*)d_in[6];
  const float* wv    = (const float*)d_in[7];
  const float* bv    = (const float*)d_in[8];
  const float* wo    = (const float*)d_in[9];
  const float* bo    = (const float*)d_in[10];
  float* out = (float*)d_out;

  char* ws = (char*)d_ws;
  const size_t SZ = (size_t)16384 * 512;
  u16* h    = (u16*)(ws);                 // 16 MB
  u16* q    = (u16*)(ws + SZ * 2);        // 16 MB (pre-scaled by C^-0.5)
  u16* k    = (u16*)(ws + SZ * 4);        // 16 MB
  u16* v8   = (u16*)(ws + SZ * 6);        // 16 MB, [B][N/8][C^(blk&3)][8]
  u16* aout = (u16*)(ws + SZ * 8);        // 16 MB
  u16* wT   = (u16*)(ws + SZ * 10);       // 4 x 512KB
  float* part  = (float*)(ws + SZ * 10 + 4 * 262144 * 2);
  float* stats = part + 2048;

  gn_partial<<<dim3(8, 32, 4), 256, 0, stream>>>(x, part);
  gn_finalize<<<1, 128, 0, stream>>>(part, stats);
  gn_apply<<<8192, 256, 0, stream>>>(x, gamma, beta, stats, h);

  wcast_t4<<<4096, 256, 0, stream>>>(wq, wk, wv, wo, wT);

  const float qs = 0.044194173824159216f;  // 512^-0.5
  gemm_qkv<<<dim3(128, 12), 256, 0, stream>>>(h, wT, bq, bk, bv, q, k, v8, qs);

  attn_kernel<<<256, 512, 0, stream>>>(q, k, v8, aout);

  gemm_oproj<<<dim3(128, 4), 256, 0, stream>>>(aout, wT + 3 * 262144, bo, x, out);
}